// Round 7
// baseline (99.411 us; speedup 1.0000x reference)
//
#include <hip/hip_runtime.h>
#include <hip/hip_bf16.h>

// MicrotubuleAttention — exact algebraic reduction + bf16 MFMA, FUSED.
//
// GTP penalty: (1 - exp(-gamma*dist))*(-1e9), gamma >= 1e-4 => every
// off-diagonal softmax argument <= -9.9e4 => expf underflows to exactly 0.
// Softmax is exactly one-hot at k==q, so attention output == V_rep and
//   out = (x @ Wv) @ Weff        (4.3 GFLOP total)
// with Weff[c][m] = sum_{r=0..3} Wo[(4*(c>>6)+r)*64 + (c&63)][m]  (GQA fold).
// RoPE/Q/K/polarity are dead code.
//
// Single persistent kernel (256 blocks -> co-resident at any occupancy>=1/CU),
// 3 phases separated by device-scope grid barriers:
//   0. WvT = bf16(Wv^T); WeffT = bf16(fold(Wo)^T)
//   A. Vb  = bf16(x) @ WvT^T    (x read as f32 via global_load_lds; cvt in
//                                fragment-read path)            [4096,256]
//   B. out = Vb @ WeffT^T       (R5-verified pipeline, 2 tiles/block)
// GEMM loops: triple-buffered LDS, depth-2 prefetch, counted vmcnt(6)
// (never 0 mid-loop), one s_barrier per K-step, XCD-chunked swizzle.

using bf16x8 = __attribute__((ext_vector_type(8))) short;
using f32x4  = __attribute__((ext_vector_type(4))) float;

static constexpr int DMODEL = 1024;
static constexpr int KVDIM  = 256;   // H_KV * D_HEAD
static constexpr int ROWS   = 4096;  // B * T
static constexpr int NBLK   = 256;   // <= #CUs: co-residency guaranteed

__device__ inline unsigned short f2bf(float f) {
    __hip_bfloat16 h = __float2bfloat16(f);   // RNE
    return *reinterpret_cast<unsigned short*>(&h);
}

// Device-scope grid barrier. slot must be zeroed before kernel launch.
__device__ inline void grid_barrier(unsigned* slot, unsigned nb) {
    __syncthreads();                       // all block stores retired (vmcnt 0)
    if (threadIdx.x == 0) {
        __threadfence();                   // release: publish L2 to device
        atomicAdd(slot, 1u);
        while (atomicMax(slot, 0u) < nb)   // atomic read, device scope
            __builtin_amdgcn_s_sleep(8);
        __threadfence();                   // acquire
    }
    __syncthreads();
}

__global__ __launch_bounds__(256, 2) void fused_kernel(
    const float* __restrict__ x,
    const float* __restrict__ Wv,
    const float* __restrict__ Wo,
    unsigned short* __restrict__ WvT,
    unsigned short* __restrict__ WeffT,
    unsigned short* __restrict__ Vb,
    float* __restrict__ out,
    unsigned* __restrict__ bar)
{
    __shared__ __align__(16) char smem[73728];   // 72 KB, phase-shared
    const int bid  = blockIdx.x;
    const int tid  = threadIdx.x;
    const int lane = tid & 63;
    const int w    = tid >> 6;        // wave 0..3
    const int wr   = w >> 1;
    const int wc   = w & 1;
    const int lr   = lane & 15;       // fragment row/col
    const int kg   = (lane >> 4) * 8; // fragment k-group base
    const int rg   = (lane >> 4) * 4; // C/D row group

    // ---------------- phase 0: weights prep ----------------
    {
        const int gt = bid * 256 + tid;               // 0..65535
        #pragma unroll
        for (int r = 0; r < 4; ++r) {                 // WvT[c][d] = Wv[d][c]
            int idx = gt + r * 65536;                 // 256K elems
            int d = idx & (DMODEL - 1), c = idx >> 10;
            WvT[idx] = f2bf(Wv[(size_t)d * KVDIM + c]);
        }
        #pragma unroll
        for (int r = 0; r < 4; ++r) {                 // WeffT[m][c], m-fast
            int i2 = gt + r * 65536;                  // 256K elems
            int m = i2 & (DMODEL - 1), c = i2 >> 10;
            const float* bp =
                Wo + (size_t)((c >> 6) * 256 + (c & 63)) * DMODEL + m;
            float s = bp[0] + bp[(size_t)64 * DMODEL]
                    + bp[(size_t)128 * DMODEL] + bp[(size_t)192 * DMODEL];
            WeffT[(size_t)m * KVDIM + c] = f2bf(s);
        }
    }
    grid_barrier(bar + 0, NBLK);

    // ---------------- phase A: Vb = bf16(x) @ WvT^T ----------------
    // 256 tiles of 64x64, K=1024 (nt=16). A staged as f32 (16KB/buf),
    // converted to bf16 in the fragment-read path.
    {
        float* Af = (float*)smem;                   // 3 x [64*64] f32 (48 KB)
        short* Bs = (short*)(smem + 49152);         // 3 x [64*64] bf16 (24 KB)
        const int swz  = (bid & 7) * 32 + (bid >> 3);   // XCD-chunked
        const int brow = (swz >> 2) * 64;
        const int bcol = (swz & 3) * 64;

        auto stage = [&](int buf, int kt) {
            #pragma unroll
            for (int i = 0; i < 4; ++i) {           // A: 16 chunks of 4 rows
                int ch = w * 4 + i;
                const float* g =
                    x + (size_t)(brow + ch * 4 + (lane >> 4)) * DMODEL
                      + kt + (lane & 15) * 4;
                __builtin_amdgcn_global_load_lds(
                    (const __attribute__((address_space(1))) void*)g,
                    (__attribute__((address_space(3))) void*)
                        (Af + buf * 4096 + ch * 256),
                    16, 0, 0);
            }
            #pragma unroll
            for (int i = 0; i < 2; ++i) {           // B: 8 chunks of 8 cols
                int ch = w * 2 + i;
                const unsigned short* g =
                    WvT + (size_t)(bcol + ch * 8 + (lane >> 3)) * DMODEL
                        + kt + (lane & 7) * 8;
                __builtin_amdgcn_global_load_lds(
                    (const __attribute__((address_space(1))) void*)g,
                    (__attribute__((address_space(3))) void*)
                        (Bs + buf * 4096 + ch * 512),
                    16, 0, 0);
            }
        };

        f32x4 acc[2][2] = {};
        stage(0, 0); stage(1, 64);
        int bc = 0;
        for (int t = 0; t < 16; ++t) {
            if (t < 15) asm volatile("s_waitcnt vmcnt(6)" ::: "memory");
            else        asm volatile("s_waitcnt vmcnt(0)" ::: "memory");
            __builtin_amdgcn_s_barrier();
            int bs = bc + 2; if (bs >= 3) bs -= 3;
            if (t + 2 < 16) stage(bs, (t + 2) << 6);
            #pragma unroll
            for (int ks = 0; ks < 2; ++ks) {
                bf16x8 a[2], b[2];
                #pragma unroll
                for (int m = 0; m < 2; ++m) {
                    const float* ap = Af + bc * 4096
                        + (wr * 32 + m * 16 + lr) * 64 + ks * 32 + kg;
                    float4 f0 = *reinterpret_cast<const float4*>(ap);
                    float4 f1 = *reinterpret_cast<const float4*>(ap + 4);
                    bf16x8 av;
                    av[0] = (short)f2bf(f0.x); av[1] = (short)f2bf(f0.y);
                    av[2] = (short)f2bf(f0.z); av[3] = (short)f2bf(f0.w);
                    av[4] = (short)f2bf(f1.x); av[5] = (short)f2bf(f1.y);
                    av[6] = (short)f2bf(f1.z); av[7] = (short)f2bf(f1.w);
                    a[m] = av;
                }
                #pragma unroll
                for (int n = 0; n < 2; ++n)
                    b[n] = *reinterpret_cast<const bf16x8*>(
                        Bs + bc * 4096 + (wc * 32 + n * 16 + lr) * 64
                           + ks * 32 + kg);
                #pragma unroll
                for (int m = 0; m < 2; ++m)
                    #pragma unroll
                    for (int n = 0; n < 2; ++n)
                        acc[m][n] = __builtin_amdgcn_mfma_f32_16x16x32_bf16(
                            a[m], b[n], acc[m][n], 0, 0, 0);
            }
            bc = (bc == 2) ? 0 : bc + 1;
        }
        #pragma unroll
        for (int m = 0; m < 2; ++m)
            #pragma unroll
            for (int n = 0; n < 2; ++n)
                #pragma unroll
                for (int j = 0; j < 4; ++j) {
                    size_t row = brow + wr * 32 + m * 16 + rg + j;
                    size_t col = bcol + wc * 32 + n * 16 + lr;
                    Vb[row * KVDIM + col] = f2bf(acc[m][n][j]);
                }
    }
    grid_barrier(bar + 1, NBLK);

    // ---------------- phase B: out = Vb @ WeffT^T ----------------
    // 512 tiles of 128x64, K=256 (nt=4); 2 tiles/block, adjacent bcols.
    {
        short* As = (short*)smem;                   // 3 x [128*64] (48 KB)
        short* Bs = (short*)(smem + 49152);         // 3 x [64*64]  (24 KB)
        const int lrow8 = lane >> 3;
        const int lkoff = (lane & 7) * 8;
        const int swz   = (bid & 7) * 32 + (bid >> 3);

        for (int rep = 0; rep < 2; ++rep) {
            const int tile = swz * 2 + rep;
            const int brow = (tile >> 4) * 128;
            const int bcol = (tile & 15) * 64;
            __syncthreads();   // previous rep's LDS reads complete

            auto stage = [&](int buf, int kt) {
                #pragma unroll
                for (int i = 0; i < 4; ++i) {       // A: 16 chunks of 8 rows
                    int ch = w * 4 + i;
                    const unsigned short* g =
                        Vb + (size_t)(brow + ch * 8 + lrow8) * KVDIM
                           + kt + lkoff;
                    __builtin_amdgcn_global_load_lds(
                        (const __attribute__((address_space(1))) void*)g,
                        (__attribute__((address_space(3))) void*)
                            (As + buf * 8192 + ch * 512),
                        16, 0, 0);
                }
                #pragma unroll
                for (int i = 0; i < 2; ++i) {       // B: 8 chunks of 8 cols
                    int ch = w * 2 + i;
                    const unsigned short* g =
                        WeffT + (size_t)(bcol + ch * 8 + lrow8) * KVDIM
                              + kt + lkoff;
                    __builtin_amdgcn_global_load_lds(
                        (const __attribute__((address_space(1))) void*)g,
                        (__attribute__((address_space(3))) void*)
                            (Bs + buf * 4096 + ch * 512),
                        16, 0, 0);
                }
            };

            f32x4 acc[4][2] = {};
            stage(0, 0); stage(1, 64);
            int bc = 0;
            for (int t = 0; t < 4; ++t) {
                if (t < 3) asm volatile("s_waitcnt vmcnt(6)" ::: "memory");
                else       asm volatile("s_waitcnt vmcnt(0)" ::: "memory");
                __builtin_amdgcn_s_barrier();
                int bs = bc + 2; if (bs >= 3) bs -= 3;
                if (t + 2 < 4) stage(bs, (t + 2) << 6);
                #pragma unroll
                for (int ks = 0; ks < 2; ++ks) {
                    bf16x8 a[4], b[2];
                    #pragma unroll
                    for (int m = 0; m < 4; ++m)
                        a[m] = *reinterpret_cast<const bf16x8*>(
                            As + bc * 8192 + (wr * 64 + m * 16 + lr) * 64
                               + ks * 32 + kg);
                    #pragma unroll
                    for (int n = 0; n < 2; ++n)
                        b[n] = *reinterpret_cast<const bf16x8*>(
                            Bs + bc * 4096 + (wc * 32 + n * 16 + lr) * 64
                               + ks * 32 + kg);
                    #pragma unroll
                    for (int m = 0; m < 4; ++m)
                        #pragma unroll
                        for (int n = 0; n < 2; ++n)
                            acc[m][n] = __builtin_amdgcn_mfma_f32_16x16x32_bf16(
                                a[m], b[n], acc[m][n], 0, 0, 0);
                }
                bc = (bc == 2) ? 0 : bc + 1;
            }
            #pragma unroll
            for (int m = 0; m < 4; ++m)
                #pragma unroll
                for (int n = 0; n < 2; ++n)
                    #pragma unroll
                    for (int j = 0; j < 4; ++j) {
                        size_t row = brow + wr * 64 + m * 16 + rg + j;
                        size_t col = bcol + wc * 32 + n * 16 + lr;
                        out[row * DMODEL + col] = acc[m][n][j];
                    }
        }
    }
}

extern "C" void kernel_launch(void* const* d_in, const int* in_sizes, int n_in,
                              void* d_out, int out_size, void* d_ws, size_t ws_size,
                              hipStream_t stream) {
    const float* x  = (const float*)d_in[0];   // (4096, 1024)
    const float* Wv = (const float*)d_in[3];   // (1024, 256)
    const float* Wo = (const float*)d_in[4];   // (1024, 1024)
    float* out = (float*)d_out;                // (4096, 1024) f32

    unsigned short* WvT   = (unsigned short*)d_ws;           // 0.5 MB [c][d]
    unsigned short* WeffT = WvT   + (size_t)KVDIM * DMODEL;  // 0.5 MB [m][c]
    unsigned short* Vb    = WeffT + (size_t)DMODEL * KVDIM;  // 2 MB   [r][c]
    unsigned*       bar   = (unsigned*)(Vb + (size_t)ROWS * KVDIM);

    hipMemsetAsync(bar, 0, 2 * sizeof(unsigned), stream);   // zero barrier slots
    fused_kernel<<<NBLK, 256, 0, stream>>>(x, Wv, Wo, WvT, WeffT, Vb, out, bar);
}

// Round 8
// 45.194 us; speedup vs baseline: 2.1997x; 2.1997x over previous
//
#include <hip/hip_runtime.h>
#include <hip/hip_bf16.h>

// MicrotubuleAttention — exact algebraic reduction + bf16 MFMA.
//
// GTP penalty: (1 - exp(-gamma*dist))*(-1e9), gamma >= 1e-4 => every
// off-diagonal softmax argument <= -9.9e4 => expf underflows to exactly 0.
// Softmax is exactly one-hot at k==q, so attention output == V_rep and
//   out = (x @ Wv) @ Weff        (4.3 GFLOP total)
// with Weff[c][m] = sum_{r=0..3} Wo[(4*(c>>6)+r)*64 + (c&63)][m]  (GQA fold).
// RoPE/Q/K/polarity are dead code.  Pipeline (3 launches):
//   1. prepW: WvT = bf16(Wv^T); WeffT = bf16(fold(Wo)^T)   (weights only)
//   2. Vb    = bf16(x) @ WvT^T   [4096,256]  — x staged as f32 via
//      global_load_lds, cvt to bf16 at fragment read (no xb round trip)
//   3. out   = Vb @ WeffT^T      [4096,1024] f32
// GEMM loops: triple-buffered LDS, depth-2 prefetch, counted s_waitcnt
// vmcnt(LP) (never 0 mid-loop), ONE s_barrier per K-step, XCD-chunked
// swizzle (T1), and T2 XOR bank-swizzle via pre-swizzled GLOBAL source +
// swizzled LDS read (global_load_lds dest stays linear — rule #21).

using bf16x8 = __attribute__((ext_vector_type(8))) short;
using f32x4  = __attribute__((ext_vector_type(4))) float;

static constexpr int DMODEL = 1024;
static constexpr int KVDIM  = 256;   // H_KV * D_HEAD
static constexpr int ROWS   = 4096;  // B * T

__device__ inline unsigned short f2bf(float f) {
    __hip_bfloat16 h = __float2bfloat16(f);   // RNE
    return *reinterpret_cast<unsigned short*>(&h);
}

// ---- weights prep (R6-verified) ------------------------------------------
static constexpr int WVT_BLOCKS  = (DMODEL * KVDIM) / 256;   // 1024
static constexpr int FOLD_BLOCKS = (DMODEL * KVDIM) / 256;   // 1024

__global__ void prepw_kernel(const float* __restrict__ Wv,
                             const float* __restrict__ Wo,
                             unsigned short* __restrict__ WvT,
                             unsigned short* __restrict__ WeffT) {
    const int b = blockIdx.x;
    const int t = threadIdx.x;
    if (b < WVT_BLOCKS) {
        int idx = b * 256 + t;                     // WvT[c][d] = bf16(Wv[d][c])
        int d = idx & (DMODEL - 1);
        int c = idx >> 10;
        WvT[idx] = f2bf(Wv[(size_t)d * KVDIM + c]);
    } else {
        int idx = (b - WVT_BLOCKS) * 256 + t;      // m-fast
        int m = idx & (DMODEL - 1), c = idx >> 10;
        const float* bp =
            Wo + (size_t)((c >> 6) * 256 + (c & 63)) * DMODEL + m;
        float s = bp[0] + bp[(size_t)64 * DMODEL]
                + bp[(size_t)128 * DMODEL] + bp[(size_t)192 * DMODEL];
        WeffT[(size_t)m * KVDIM + c] = f2bf(s);
    }
}

// ---- gemmA: Vb[4096][256] = bf16(x) @ WvT^T ------------------------------
// BM=64, BN=32, BK=64; grid 8x64 = 512 blocks (2/CU). 4 waves (2x2),
// wave tile 32x16 (AM=2, AN=1). A staged as f32 (16KB/buf) via
// global_load_lds with inverse-swizzled source; cvt f32->bf16 at read.
// LP = 4(A) + 1(B) = 5 loads/wave/stage.
__launch_bounds__(256, 2)
__global__ void gemm_xwv(const float* __restrict__ X,
                         const unsigned short* __restrict__ WvT,
                         unsigned short* __restrict__ Vb) {
    __shared__ float Af[3][64 * 64];    // 3 x 16 KB
    __shared__ short Bs[3][32 * 64];    // 3 x  4 KB

    // T1: XCD-chunked swizzle (nwg = 512)
    const int gx  = gridDim.x;                    // 8
    const int bid = blockIdx.y * gx + blockIdx.x;
    const int cpx = (gx * gridDim.y) >> 3;        // 64
    const int swz = (bid & 7) * cpx + (bid >> 3);
    const int brow = (swz / gx) * 64;
    const int bcol = (swz % gx) * 32;

    const int tid  = threadIdx.x;
    const int lane = tid & 63;
    const int w    = tid >> 6;
    const int wr   = w >> 1;          // 0..1: 32-row half
    const int wc   = w & 1;           // 0..1: 16-col half
    const int lr   = lane & 15;
    const int rg   = (lane >> 4) * 4;

    // A staging (f32): 16 chunks of 4 rows; lane -> row l>>4, 16B chunk l&15.
    // Source k-offset inverse-swizzled: 32B group ^= (row&7), 16B half kept.
    const int arow_in_ch = lane >> 4;             // 0..3
    const int ac16       = lane & 15;             // 16B chunk
    // B staging (bf16): 8 rows x 8 chunks per instr; source chunk ^= row&7.
    const int brow_in_ch = lane >> 3;             // 0..7
    const int bkoff      = ((lane & 7) ^ (lane >> 3)) * 8;

    f32x4 acc[2] = {};                 // m=0,1 (AN=1)

    auto stage = [&](int buf, int kt) {
        #pragma unroll
        for (int i = 0; i < 4; ++i) {
            const int ch  = w * 4 + i;            // 0..15
            const int row = ch * 4 + arow_in_ch;  // 0..63
            const int kof = (((ac16 >> 1) ^ (row & 7)) * 2 + (ac16 & 1)) * 4;
            const float* g = X + (size_t)(brow + row) * DMODEL + kt + kof;
            __builtin_amdgcn_global_load_lds(
                (const __attribute__((address_space(1))) void*)g,
                (__attribute__((address_space(3))) void*)(&Af[buf][ch * 256]),
                16, 0, 0);
        }
        {
            const int ch  = w;                    // 0..3
            const int row = ch * 8 + brow_in_ch;  // 0..31
            const unsigned short* g =
                WvT + (size_t)(bcol + row) * DMODEL + kt + bkoff;
            __builtin_amdgcn_global_load_lds(
                (const __attribute__((address_space(1))) void*)g,
                (__attribute__((address_space(3))) void*)(&Bs[buf][ch * 512]),
                16, 0, 0);
        }
    };

    constexpr int nt = DMODEL / 64;    // 16
    stage(0, 0);
    stage(1, 64);
    int bc = 0;
    for (int t = 0; t < nt; ++t) {
        if (t + 1 < nt) asm volatile("s_waitcnt vmcnt(5)" ::: "memory");
        else            asm volatile("s_waitcnt vmcnt(0)" ::: "memory");
        __builtin_amdgcn_s_barrier();

        int bs = bc + 2; if (bs >= 3) bs -= 3;
        if (t + 2 < nt) stage(bs, (t + 2) << 6);

        #pragma unroll
        for (int ks = 0; ks < 2; ++ks) {
            const int q = ks * 4 + (lane >> 4);   // logical 32B/16B group
            bf16x8 a[2], b;
            #pragma unroll
            for (int m = 0; m < 2; ++m) {
                const int row = wr * 32 + m * 16 + lr;
                const float* ap =
                    &Af[bc][row * 64 + ((q ^ (lr & 7)) * 8)];
                float4 f0 = *reinterpret_cast<const float4*>(ap);
                float4 f1 = *reinterpret_cast<const float4*>(ap + 4);
                bf16x8 av;
                av[0] = (short)f2bf(f0.x); av[1] = (short)f2bf(f0.y);
                av[2] = (short)f2bf(f0.z); av[3] = (short)f2bf(f0.w);
                av[4] = (short)f2bf(f1.x); av[5] = (short)f2bf(f1.y);
                av[6] = (short)f2bf(f1.z); av[7] = (short)f2bf(f1.w);
                a[m] = av;
            }
            {
                const int row = wc * 16 + lr;
                b = *reinterpret_cast<const bf16x8*>(
                    &Bs[bc][row * 64 + ((q ^ (lr & 7)) * 8)]);
            }
            #pragma unroll
            for (int m = 0; m < 2; ++m)
                acc[m] = __builtin_amdgcn_mfma_f32_16x16x32_bf16(
                    a[m], b, acc[m], 0, 0, 0);
        }
        bc = (bc == 2) ? 0 : bc + 1;
    }

    // C/D layout: col = lane&15, row = (lane>>4)*4 + reg
    #pragma unroll
    for (int m = 0; m < 2; ++m)
        #pragma unroll
        for (int j = 0; j < 4; ++j) {
            const size_t row = brow + wr * 32 + m * 16 + rg + j;
            const size_t col = bcol + wc * 16 + lr;
            Vb[row * KVDIM + col] = f2bf(acc[m][j]);
        }
}

// ---- gemmB: out[4096][1024] = Vb @ WeffT^T  (R5 structure + T2 swizzle) --
// BM=128, BN=64, BK=64; grid 16x32 = 512 blocks (2/CU). LP = 4+2 = 6.
__launch_bounds__(256, 2)
__global__ void gemm_vb_weff(const unsigned short* __restrict__ A,
                             const unsigned short* __restrict__ Bt,
                             float* __restrict__ C) {
    constexpr int K = KVDIM;          // 256
    constexpr int N = DMODEL;         // 1024

    __shared__ short As[3][128 * 64];   // 3 x 16 KB
    __shared__ short Bs[3][64 * 64];    // 3 x  8 KB

    const int gx  = gridDim.x;                    // 16
    const int bid = blockIdx.y * gx + blockIdx.x;
    const int cpx = (gx * gridDim.y) >> 3;        // 64
    const int swz = (bid & 7) * cpx + (bid >> 3);
    const int brow = (swz / gx) * 128;
    const int bcol = (swz % gx) * 64;

    const int tid  = threadIdx.x;
    const int lane = tid & 63;
    const int w    = tid >> 6;
    const int wr   = w >> 1;
    const int wc   = w & 1;
    const int lr   = lane & 15;
    const int rg   = (lane >> 4) * 4;

    const int lrow8 = lane >> 3;
    const int skoff = ((lane & 7) ^ (lane >> 3)) * 8;   // inverse-swizzled src

    f32x4 acc[4][2] = {};

    auto stage = [&](int buf, int kt) {
        #pragma unroll
        for (int i = 0; i < 4; ++i) {
            const int ch = w * 4 + i;                   // 0..15
            const unsigned short* g =
                A + (size_t)(brow + ch * 8 + lrow8) * K + kt + skoff;
            __builtin_amdgcn_global_load_lds(
                (const __attribute__((address_space(1))) void*)g,
                (__attribute__((address_space(3))) void*)(&As[buf][ch * 512]),
                16, 0, 0);
        }
        #pragma unroll
        for (int i = 0; i < 2; ++i) {
            const int ch = w * 2 + i;                   // 0..7
            const unsigned short* g =
                Bt + (size_t)(bcol + ch * 8 + lrow8) * K + kt + skoff;
            __builtin_amdgcn_global_load_lds(
                (const __attribute__((address_space(1))) void*)g,
                (__attribute__((address_space(3))) void*)(&Bs[buf][ch * 512]),
                16, 0, 0);
        }
    };

    constexpr int nt = K / 64;          // 4
    stage(0, 0);
    stage(1, 64);
    int bc = 0;
    for (int t = 0; t < nt; ++t) {
        if (t + 1 < nt) asm volatile("s_waitcnt vmcnt(6)" ::: "memory");
        else            asm volatile("s_waitcnt vmcnt(0)" ::: "memory");
        __builtin_amdgcn_s_barrier();

        int bs = bc + 2; if (bs >= 3) bs -= 3;
        if (t + 2 < nt) stage(bs, (t + 2) << 6);

        #pragma unroll
        for (int ks = 0; ks < 2; ++ks) {
            const int q = ks * 4 + (lane >> 4);
            bf16x8 a[4], b[2];
            #pragma unroll
            for (int m = 0; m < 4; ++m) {
                const int row = wr * 64 + m * 16 + lr;
                a[m] = *reinterpret_cast<const bf16x8*>(
                    &As[bc][row * 64 + ((q ^ (lr & 7)) * 8)]);
            }
            #pragma unroll
            for (int n = 0; n < 2; ++n) {
                const int row = wc * 32 + n * 16 + lr;
                b[n] = *reinterpret_cast<const bf16x8*>(
                    &Bs[bc][row * 64 + ((q ^ (lr & 7)) * 8)]);
            }
            #pragma unroll
            for (int m = 0; m < 4; ++m)
                #pragma unroll
                for (int n = 0; n < 2; ++n)
                    acc[m][n] = __builtin_amdgcn_mfma_f32_16x16x32_bf16(
                        a[m], b[n], acc[m][n], 0, 0, 0);
        }
        bc = (bc == 2) ? 0 : bc + 1;
    }

    #pragma unroll
    for (int m = 0; m < 4; ++m)
        #pragma unroll
        for (int n = 0; n < 2; ++n)
            #pragma unroll
            for (int j = 0; j < 4; ++j) {
                const size_t row = brow + wr * 64 + m * 16 + rg + j;
                const size_t col = bcol + wc * 32 + n * 16 + lr;
                C[row * N + col] = acc[m][n][j];
            }
}

extern "C" void kernel_launch(void* const* d_in, const int* in_sizes, int n_in,
                              void* d_out, int out_size, void* d_ws, size_t ws_size,
                              hipStream_t stream) {
    const float* x  = (const float*)d_in[0];   // (4096, 1024)
    const float* Wv = (const float*)d_in[3];   // (1024, 256)
    const float* Wo = (const float*)d_in[4];   // (1024, 1024)
    float* out = (float*)d_out;                // (4096, 1024) f32

    unsigned short* WvT   = (unsigned short*)d_ws;           // 0.5 MB [c][d]
    unsigned short* WeffT = WvT   + (size_t)KVDIM * DMODEL;  // 0.5 MB [m][c]
    unsigned short* Vb    = WeffT + (size_t)DMODEL * KVDIM;  // 2 MB   [r][c]

    prepw_kernel<<<WVT_BLOCKS + FOLD_BLOCKS, 256, 0, stream>>>(
        Wv, Wo, WvT, WeffT);

    // Vb[r][c] = sum_d bf16(x[r][d]) * WvT[c][d]   (M=4096, N=256, K=1024)
    gemm_xwv<<<dim3(KVDIM / 32, ROWS / 64), 256, 0, stream>>>(x, WvT, Vb);

    // out[r][m] = sum_c Vb[r][c] * WeffT[m][c]     (M=4096, N=1024, K=256)
    gemm_vb_weff<<<dim3(DMODEL / 64, ROWS / 128), 256, 0, stream>>>(
        Vb, WeffT, out);
}

// Round 9
// 35.444 us; speedup vs baseline: 2.8048x; 1.2751x over previous
//
#include <hip/hip_runtime.h>
#include <hip/hip_bf16.h>

// MicrotubuleAttention — exact algebraic reduction + bf16 MFMA.
//
// GTP penalty: (1 - exp(-gamma*dist))*(-1e9), gamma >= 1e-4 => every
// off-diagonal softmax argument <= -9.9e4 => expf underflows to exactly 0.
// Softmax is exactly one-hot at k==q, so attention output == V_rep and
//   out = (x @ Wv) @ Weff        (4.3 GFLOP total)
// with Weff[c][m] = sum_{r=0..3} Wo[(4*(c>>6)+r)*64 + (c&63)][m]  (GQA fold).
// RoPE/Q/K/polarity are dead code.  Pipeline (3 launches):
//   1. prep:  xb = bf16(x); WvT = bf16(Wv^T); WeffT = bf16(fold(Wo)^T)
//             (WvT/WeffT built via LDS tile transpose: coalesced R+W)
//   2. Vb    = xb @ WvT^T    (MFMA, bf16 out)  [4096,256]   K=1024
//   3. out   = Vb @ WeffT^T  (MFMA, f32 out)   [4096,1024]  K=256
//             (C-write via LDS bounce -> coalesced float4 stores)
// GEMM loops (R5-verified, untouched): triple-buffered LDS, depth-2
// prefetch, counted s_waitcnt vmcnt (never 0 mid-loop), one s_barrier per
// K-step, XCD-chunked swizzle (T1).

using bf16x8 = __attribute__((ext_vector_type(8))) short;
using f32x4  = __attribute__((ext_vector_type(4))) float;

static constexpr int DMODEL = 1024;
static constexpr int KVDIM  = 256;   // H_KV * D_HEAD
static constexpr int ROWS   = 4096;  // B * T

__device__ inline unsigned short f2bf(float f) {
    __hip_bfloat16 h = __float2bfloat16(f);   // RNE
    return *reinterpret_cast<unsigned short*>(&h);
}

// ---- fused prep: block-range partitioned -------------------------------
static constexpr int XCVT_BLOCKS = (ROWS * DMODEL) / 4 / 256;   // 4096
static constexpr int WVT_TILES   = (DMODEL / 64) * (KVDIM / 64);   // 64
static constexpr int WEFF_TILES  = (DMODEL / 64) * (KVDIM / 64);   // 64

__global__ void prep_kernel(const float* __restrict__ x,
                            const float* __restrict__ Wv,
                            const float* __restrict__ Wo,
                            unsigned short* __restrict__ xb,
                            unsigned short* __restrict__ WvT,
                            unsigned short* __restrict__ WeffT) {
    __shared__ float ld[64][65];     // padded: conflict-free column reads
    const int b = blockIdx.x;
    const int t = threadIdx.x;

    if (b < XCVT_BLOCKS) {
        // xb = bf16(x), fully coalesced float4 -> ushort4
        int i = b * 256 + t;
        float4 v = reinterpret_cast<const float4*>(x)[i];
        ushort4 o;
        o.x = f2bf(v.x); o.y = f2bf(v.y); o.z = f2bf(v.z); o.w = f2bf(v.w);
        reinterpret_cast<ushort4*>(xb)[i] = o;
    } else if (b < XCVT_BLOCKS + WVT_TILES) {
        // WvT[c][d] = bf16(Wv[d][c]) via 64x64 LDS transpose tile
        const int tile = b - XCVT_BLOCKS;
        const int d0 = (tile & 15) * 64;          // 16 tiles along d
        const int c0 = (tile >> 4) * 64;          // 4 tiles along c
        #pragma unroll
        for (int i = 0; i < 4; ++i) {             // coalesced float4 reads
            int row  = i * 16 + (t >> 4);         // d-local
            int col4 = (t & 15) * 4;              // c-local
            float4 v = *reinterpret_cast<const float4*>(
                Wv + (size_t)(d0 + row) * KVDIM + c0 + col4);
            ld[row][col4 + 0] = v.x; ld[row][col4 + 1] = v.y;
            ld[row][col4 + 2] = v.z; ld[row][col4 + 3] = v.w;
        }
        __syncthreads();
        #pragma unroll
        for (int i = 0; i < 4; ++i) {             // coalesced ushort4 writes
            int crow = i * 16 + (t >> 4);         // c-local
            int dcol = (t & 15) * 4;              // d-local
            ushort4 o;
            o.x = f2bf(ld[dcol + 0][crow]);
            o.y = f2bf(ld[dcol + 1][crow]);
            o.z = f2bf(ld[dcol + 2][crow]);
            o.w = f2bf(ld[dcol + 3][crow]);
            *reinterpret_cast<ushort4*>(
                WvT + (size_t)(c0 + crow) * DMODEL + d0 + dcol) = o;
        }
    } else {
        // WeffT[m][c] = bf16(sum_r Wo[(4*(c>>6)+r)*64 + (c&63)][m])
        // via 64(m) x 64(c) LDS tile: coalesced reads + coalesced writes
        const int tile = b - XCVT_BLOCKS - WVT_TILES;
        const int m0 = (tile & 15) * 64;          // 16 tiles along m
        const int c0 = (tile >> 4) * 64;          // 4 tiles along c
        #pragma unroll
        for (int g = 0; g < 16; ++g) {            // 4 c's per pass
            int cl = g * 4 + (t >> 6);            // c-local
            int ml = t & 63;                      // m-local
            int c  = c0 + cl;
            const float* bp =
                Wo + (size_t)((c >> 6) * 256 + (c & 63)) * DMODEL + m0 + ml;
            float s = bp[0] + bp[(size_t)64 * DMODEL]
                    + bp[(size_t)128 * DMODEL] + bp[(size_t)192 * DMODEL];
            ld[cl][ml] = s;                       // [c-local][m-local]
        }
        __syncthreads();
        const int mrow = t >> 2;                  // m-local row
        const int cch  = (t & 3) * 16;            // c-local 16-chunk
        #pragma unroll
        for (int jj = 0; jj < 4; ++jj) {
            ushort4 o;
            o.x = f2bf(ld[cch + jj * 4 + 0][mrow]);
            o.y = f2bf(ld[cch + jj * 4 + 1][mrow]);
            o.z = f2bf(ld[cch + jj * 4 + 2][mrow]);
            o.w = f2bf(ld[cch + jj * 4 + 3][mrow]);
            *reinterpret_cast<ushort4*>(
                WeffT + (size_t)(m0 + mrow) * KVDIM + c0 + cch + jj * 4) = o;
        }
    }
}

// ---- gemmA: Vb[4096][256] = xb @ WvT^T  (R5-verified, unchanged) --------
// BM=BN=64, BK=64; 4 waves 2x2, wave tile 32x32. Triple-buffered LDS,
// depth-2 prefetch, counted vmcnt(4), one s_barrier per K-step.
__launch_bounds__(256, 2)
__global__ void gemm_xwv(const unsigned short* __restrict__ A,
                         const unsigned short* __restrict__ Bt,
                         unsigned short* __restrict__ Vb) {
    constexpr int K = DMODEL;        // 1024
    __shared__ short As[3][64 * 64];
    __shared__ short Bs[3][64 * 64];

    const int gx  = gridDim.x;                    // 4
    const int bid = blockIdx.y * gx + blockIdx.x;
    const int cpx = (gx * gridDim.y) >> 3;        // 32
    const int swz = (bid & 7) * cpx + (bid >> 3);
    const int brow = (swz / gx) * 64;
    const int bcol = (swz % gx) * 64;

    const int tid  = threadIdx.x;
    const int lane = tid & 63;
    const int w    = tid >> 6;
    const int wr   = w >> 1;
    const int wc   = w & 1;

    const int lrow8 = lane >> 3;
    const int lkoff = (lane & 7) * 8;
    const int lr    = lane & 15;
    const int kg    = (lane >> 4) * 8;

    f32x4 acc[2][2] = {};

    auto stage = [&](int buf, int kt) {
        #pragma unroll
        for (int i = 0; i < 2; ++i) {
            const int ch = w * 2 + i;                   // 0..7
            const unsigned short* g =
                A + (size_t)(brow + ch * 8 + lrow8) * K + kt + lkoff;
            __builtin_amdgcn_global_load_lds(
                (const __attribute__((address_space(1))) void*)g,
                (__attribute__((address_space(3))) void*)(&As[buf][ch * 512]),
                16, 0, 0);
        }
        #pragma unroll
        for (int i = 0; i < 2; ++i) {
            const int ch = w * 2 + i;
            const unsigned short* g =
                Bt + (size_t)(bcol + ch * 8 + lrow8) * K + kt + lkoff;
            __builtin_amdgcn_global_load_lds(
                (const __attribute__((address_space(1))) void*)g,
                (__attribute__((address_space(3))) void*)(&Bs[buf][ch * 512]),
                16, 0, 0);
        }
    };

    constexpr int nt = K / 64;       // 16
    stage(0, 0);
    stage(1, 64);
    int bc = 0;
    for (int t = 0; t < nt; ++t) {
        if (t + 1 < nt) asm volatile("s_waitcnt vmcnt(4)" ::: "memory");
        else            asm volatile("s_waitcnt vmcnt(0)" ::: "memory");
        __builtin_amdgcn_s_barrier();

        int bs = bc + 2; if (bs >= 3) bs -= 3;
        if (t + 2 < nt) stage(bs, (t + 2) << 6);

        #pragma unroll
        for (int ks = 0; ks < 2; ++ks) {
            bf16x8 a[2], b[2];
            #pragma unroll
            for (int m = 0; m < 2; ++m)
                a[m] = *reinterpret_cast<const bf16x8*>(
                    &As[bc][(wr * 32 + m * 16 + lr) * 64 + ks * 32 + kg]);
            #pragma unroll
            for (int n = 0; n < 2; ++n)
                b[n] = *reinterpret_cast<const bf16x8*>(
                    &Bs[bc][(wc * 32 + n * 16 + lr) * 64 + ks * 32 + kg]);
            #pragma unroll
            for (int m = 0; m < 2; ++m)
                #pragma unroll
                for (int n = 0; n < 2; ++n)
                    acc[m][n] = __builtin_amdgcn_mfma_f32_16x16x32_bf16(
                        a[m], b[n], acc[m][n], 0, 0, 0);
        }
        bc = (bc == 2) ? 0 : bc + 1;
    }

    const int rg = (lane >> 4) * 4;
    #pragma unroll
    for (int m = 0; m < 2; ++m)
        #pragma unroll
        for (int n = 0; n < 2; ++n)
            #pragma unroll
            for (int j = 0; j < 4; ++j) {
                const size_t row = brow + wr * 32 + m * 16 + rg + j;
                const size_t col = bcol + wc * 32 + n * 16 + lr;
                Vb[row * KVDIM + col] = f2bf(acc[m][n][j]);
            }
}

// ---- gemmB: out[4096][1024] = Vb @ WeffT^T ------------------------------
// BM=128, BN=64, BK=64 (R5 core) + LDS-bounce coalesced f32 epilogue.
__launch_bounds__(256, 2)
__global__ void gemm_vb_weff(const unsigned short* __restrict__ A,
                             const unsigned short* __restrict__ Bt,
                             float* __restrict__ C) {
    constexpr int K = KVDIM;          // 256
    constexpr int N = DMODEL;         // 1024

    __shared__ short As[3][128 * 64];   // 48 KB (reused by epilogue bounce)
    __shared__ short Bs[3][64 * 64];    // 24 KB

    const int gx  = gridDim.x;                    // 16
    const int bid = blockIdx.y * gx + blockIdx.x;
    const int cpx = (gx * gridDim.y) >> 3;        // 64
    const int swz = (bid & 7) * cpx + (bid >> 3);
    const int brow = (swz / gx) * 128;
    const int bcol = (swz % gx) * 64;

    const int tid  = threadIdx.x;
    const int lane = tid & 63;
    const int w    = tid >> 6;
    const int wr   = w >> 1;
    const int wc   = w & 1;

    const int lrow8 = lane >> 3;
    const int lkoff = (lane & 7) * 8;
    const int lr    = lane & 15;
    const int kg    = (lane >> 4) * 8;

    f32x4 acc[4][2] = {};

    auto stage = [&](int buf, int kt) {
        #pragma unroll
        for (int i = 0; i < 4; ++i) {
            const int ch = w * 4 + i;                   // 0..15
            const unsigned short* g =
                A + (size_t)(brow + ch * 8 + lrow8) * K + kt + lkoff;
            __builtin_amdgcn_global_load_lds(
                (const __attribute__((address_space(1))) void*)g,
                (__attribute__((address_space(3))) void*)(&As[buf][ch * 512]),
                16, 0, 0);
        }
        #pragma unroll
        for (int i = 0; i < 2; ++i) {
            const int ch = w * 2 + i;                   // 0..7
            const unsigned short* g =
                Bt + (size_t)(bcol + ch * 8 + lrow8) * K + kt + lkoff;
            __builtin_amdgcn_global_load_lds(
                (const __attribute__((address_space(1))) void*)g,
                (__attribute__((address_space(3))) void*)(&Bs[buf][ch * 512]),
                16, 0, 0);
        }
    };

    constexpr int nt = K / 64;          // 4
    stage(0, 0);
    stage(1, 64);
    int bc = 0;
    for (int t = 0; t < nt; ++t) {
        if (t + 1 < nt) asm volatile("s_waitcnt vmcnt(6)" ::: "memory");
        else            asm volatile("s_waitcnt vmcnt(0)" ::: "memory");
        __builtin_amdgcn_s_barrier();

        int bs = bc + 2; if (bs >= 3) bs -= 3;
        if (t + 2 < nt) stage(bs, (t + 2) << 6);

        #pragma unroll
        for (int ks = 0; ks < 2; ++ks) {
            bf16x8 a[4], b[2];
            #pragma unroll
            for (int m = 0; m < 4; ++m)
                a[m] = *reinterpret_cast<const bf16x8*>(
                    &As[bc][(wr * 64 + m * 16 + lr) * 64 + ks * 32 + kg]);
            #pragma unroll
            for (int n = 0; n < 2; ++n)
                b[n] = *reinterpret_cast<const bf16x8*>(
                    &Bs[bc][(wc * 32 + n * 16 + lr) * 64 + ks * 32 + kg]);
            #pragma unroll
            for (int m = 0; m < 4; ++m)
                #pragma unroll
                for (int n = 0; n < 2; ++n)
                    acc[m][n] = __builtin_amdgcn_mfma_f32_16x16x32_bf16(
                        a[m], b[n], acc[m][n], 0, 0, 0);
        }
        bc = (bc == 2) ? 0 : bc + 1;
    }

    // Epilogue: acc -> LDS [128][65] f32 -> coalesced float4 stores.
    float* Cl = reinterpret_cast<float*>(&As[0][0]);   // 33.3 KB of 48 KB
    __syncthreads();                  // K-loop LDS reads complete everywhere
    const int rg = (lane >> 4) * 4;
    #pragma unroll
    for (int m = 0; m < 4; ++m)
        #pragma unroll
        for (int n = 0; n < 2; ++n)
            #pragma unroll
            for (int j = 0; j < 4; ++j)
                Cl[(wr * 64 + m * 16 + rg + j) * 65
                   + wc * 32 + n * 16 + lr] = acc[m][n][j];
    __syncthreads();
    #pragma unroll
    for (int i = 0; i < 8; ++i) {     // 128x64 f32: 8 float4 per thread
        const int idx = i * 256 + tid;
        const int row = idx >> 4;
        const int c4  = (idx & 15) * 4;
        float4 v;
        v.x = Cl[row * 65 + c4 + 0];
        v.y = Cl[row * 65 + c4 + 1];
        v.z = Cl[row * 65 + c4 + 2];
        v.w = Cl[row * 65 + c4 + 3];
        *reinterpret_cast<float4*>(
            C + (size_t)(brow + row) * N + bcol + c4) = v;
    }
}

extern "C" void kernel_launch(void* const* d_in, const int* in_sizes, int n_in,
                              void* d_out, int out_size, void* d_ws, size_t ws_size,
                              hipStream_t stream) {
    const float* x  = (const float*)d_in[0];   // (4096, 1024)
    const float* Wv = (const float*)d_in[3];   // (1024, 256)
    const float* Wo = (const float*)d_in[4];   // (1024, 1024)
    float* out = (float*)d_out;                // (4096, 1024) f32

    unsigned short* xb    = (unsigned short*)d_ws;           // 8 MB
    unsigned short* WvT   = xb    + (size_t)ROWS * DMODEL;   // 0.5 MB [c][d]
    unsigned short* WeffT = WvT   + (size_t)KVDIM * DMODEL;  // 0.5 MB [m][c]
    unsigned short* Vb    = WeffT + (size_t)DMODEL * KVDIM;  // 2 MB   [r][c]

    prep_kernel<<<XCVT_BLOCKS + WVT_TILES + WEFF_TILES, 256, 0, stream>>>(
        x, Wv, Wo, xb, WvT, WeffT);

    // Vb[r][c] = sum_d xb[r][d] * WvT[c][d]    (M=4096, N=256, K=1024)
    gemm_xwv<<<dim3(KVDIM / 64, ROWS / 64), 256, 0, stream>>>(xb, WvT, Vb);

    // out[r][m] = sum_c Vb[r][c] * WeffT[m][c] (M=4096, N=1024, K=256)
    gemm_vb_weff<<<dim3(DMODEL / 64, ROWS / 128), 256, 0, stream>>>(
        Vb, WeffT, out);
}